// Round 3
// baseline (1905.557 us; speedup 1.0000x reference)
//
#include <hip/hip_runtime.h>
#include <math.h>

#define D1 768
#define D2R 385
#define NF 295680   // 768*385
#define KNUM 4
#define NB 8
#define NC 256

// ws layout (floats):
//   bufA [0 .. SPEC)      : scattered spectrum (4,768,385) complex; reused as SW (4,768,768) real
//   bufY [SPEC .. 2*SPEC) : stage-A output (4,768,385) complex; first 256 floats reused
//                           as conv's zero-page after stage B completes
#define SPEC_FLOATS 2365440
#define TWOPI_768 0.008181230868723419f

// ---------------- scatter: dft_weight -> dense half-spectrum -------------
__global__ __launch_bounds__(256) void scatter_kernel(
    const float* __restrict__ dw, const int* __restrict__ fh,
    const int* __restrict__ fw, float* __restrict__ spec) {
  int i = blockIdx.x * 256 + threadIdx.x;  // grid.x = 1155 exact
  int k = blockIdx.y;
  const float2 v = ((const float2*)dw)[(size_t)k * NF + i];
  int h = fh[i], w = fw[i];
  ((float2*)spec)[((size_t)k * D1 + h) * D2R + w] = v;
}

// ---------------- stage A: complex ifft along axis 0 (length 768) --------
// Y[k][m][c] = (wgt_c/768^2) * sum_h spec[k][h][c] * e^{+2pi i h m/768}
// thread tile: 2c x 8m; block tile: 64c x 64m
__global__ __launch_bounds__(256) void stageA_kernel(
    const float* __restrict__ spec, float* __restrict__ Y) {
  __shared__ float tw[768 * 2];      // twiddle table (cos,sin)
  __shared__ float Ss[32 * 64 * 2];  // [h][c] complex
  __shared__ float Es[32 * 64 * 2];  // [h][m] complex
  int t = threadIdx.x;
  int c0 = blockIdx.x * 64;
  int m0 = blockIdx.y * 64;
  int k = blockIdx.z;
  for (int i = t; i < 768; i += 256) {
    float s, c;
    sincosf((float)i * TWOPI_768, &s, &c);
    ((float2*)tw)[i] = make_float2(c, s);
  }
  int tx = t & 31, ty = t >> 5;
  float ar0[8] = {}, ai0[8] = {}, ar1[8] = {}, ai1[8] = {};

  for (int kt = 0; kt < 24; ++kt) {
    int h0 = kt * 32;
    __syncthreads();  // also covers tw init on first iter
#pragma unroll
    for (int p = 0; p < 8; ++p) {  // S tile 32h x 64c
      int idx = t + 256 * p;
      int h = idx >> 6, c = idx & 63;
      float2 v = make_float2(0.f, 0.f);
      if (c0 + c < D2R)
        v = ((const float2*)spec)[((size_t)k * D1 + h0 + h) * D2R + c0 + c];
      ((float2*)Ss)[h * 64 + c] = v;
    }
#pragma unroll
    for (int p = 0; p < 8; ++p) {  // E tile 32h x 64m from table
      int idx = t + 256 * p;
      int h = idx >> 6, m = idx & 63;
      int tt = ((h0 + h) * (m0 + m)) % 768;
      ((float2*)Es)[h * 64 + m] = ((const float2*)tw)[tt];
    }
    __syncthreads();
#pragma unroll 2
    for (int h = 0; h < 32; ++h) {
      float2 S0 = ((float2*)Ss)[h * 64 + tx];
      float2 S1 = ((float2*)Ss)[h * 64 + tx + 32];
#pragma unroll
      for (int j = 0; j < 8; ++j) {
        float2 E = ((float2*)Es)[h * 64 + ty + 8 * j];
        ar0[j] = fmaf(S0.x, E.x, ar0[j]); ar0[j] = fmaf(-S0.y, E.y, ar0[j]);
        ai0[j] = fmaf(S0.x, E.y, ai0[j]); ai0[j] = fmaf(S0.y, E.x, ai0[j]);
        ar1[j] = fmaf(S1.x, E.x, ar1[j]); ar1[j] = fmaf(-S1.y, E.y, ar1[j]);
        ai1[j] = fmaf(S1.x, E.y, ai1[j]); ai1[j] = fmaf(S1.y, E.x, ai1[j]);
      }
    }
  }
#pragma unroll
  for (int q = 0; q < 2; ++q) {
    int c = c0 + tx + 32 * q;
    if (c < D2R) {
      float scale = (c == 0 || c == D2R - 1) ? 1.6954210069444445e-6f
                                             : 3.390842013888889e-6f;
      float* ar = q ? ar1 : ar0;
      float* ai = q ? ai1 : ai0;
#pragma unroll
      for (int j = 0; j < 8; ++j) {
        int m = m0 + ty + 8 * j;
        ((float2*)Y)[((size_t)k * D1 + m) * D2R + c] =
            make_float2(ar[j] * scale, ai[j] * scale);
      }
    }
  }
}

// ---------------- stage B: real irfft along axis 1 (385 -> 768) ----------
// SW[k][m][n] = sum_c ( ReY'[m][c] cos - ImY'[m][c] sin )
// thread tile: 4n x 8m; block tile: 128n x 64m
__global__ __launch_bounds__(256) void stageB_kernel(
    const float* __restrict__ Y, float* __restrict__ SW) {
  __shared__ float tw[768 * 2];
  __shared__ float Ys[32 * 65 * 2];   // [c][m] complex, padded
  __shared__ float Tt[32 * 128 * 2];  // [c][n] (cos,sin)
  int t = threadIdx.x;
  int n0 = blockIdx.x * 128;
  int m0 = blockIdx.y * 64;
  int k = blockIdx.z;
  for (int i = t; i < 768; i += 256) {
    float s, c;
    sincosf((float)i * TWOPI_768, &s, &c);
    ((float2*)tw)[i] = make_float2(c, s);
  }
  int tx = t & 31, ty = t >> 5;
  float acc[4][8] = {};

  for (int kt = 0; kt < 13; ++kt) {
    int cb = kt * 32;
    __syncthreads();
#pragma unroll
    for (int p = 0; p < 8; ++p) {  // Y tile transposed [c][m]
      int idx = t + 256 * p;
      int m = idx >> 5, c = idx & 31;
      float2 v = make_float2(0.f, 0.f);
      if (cb + c < D2R)
        v = ((const float2*)Y)[((size_t)k * D1 + m0 + m) * D2R + cb + c];
      ((float2*)Ys)[c * 65 + m] = v;
    }
#pragma unroll
    for (int p = 0; p < 16; ++p) {  // T tile 32c x 128n from table
      int idx = t + 256 * p;
      int c = idx >> 7, n = idx & 127;
      int tt = ((cb + c) * (n0 + n)) % 768;
      ((float2*)Tt)[c * 128 + n] = ((const float2*)tw)[tt];
    }
    __syncthreads();
#pragma unroll 2
    for (int c = 0; c < 32; ++c) {
      float2 T0 = ((float2*)Tt)[c * 128 + tx];
      float2 T1 = ((float2*)Tt)[c * 128 + tx + 32];
      float2 T2 = ((float2*)Tt)[c * 128 + tx + 64];
      float2 T3 = ((float2*)Tt)[c * 128 + tx + 96];
#pragma unroll
      for (int j = 0; j < 8; ++j) {
        float2 Yv = ((float2*)Ys)[c * 65 + ty + 8 * j];
        acc[0][j] = fmaf(Yv.x, T0.x, acc[0][j]);
        acc[0][j] = fmaf(-Yv.y, T0.y, acc[0][j]);
        acc[1][j] = fmaf(Yv.x, T1.x, acc[1][j]);
        acc[1][j] = fmaf(-Yv.y, T1.y, acc[1][j]);
        acc[2][j] = fmaf(Yv.x, T2.x, acc[2][j]);
        acc[2][j] = fmaf(-Yv.y, T2.y, acc[2][j]);
        acc[3][j] = fmaf(Yv.x, T3.x, acc[3][j]);
        acc[3][j] = fmaf(-Yv.y, T3.y, acc[3][j]);
      }
    }
  }
#pragma unroll
  for (int j = 0; j < 8; ++j) {
    int m = m0 + ty + 8 * j;
    size_t base = ((size_t)k * D1 + m) * D1 + n0 + tx;
#pragma unroll
    for (int q = 0; q < 4; ++q) SW[base + 32 * q] = acc[q][j];
  }
}

// ---------------- conv: per-batch 3x3 grouped conv -----------------------
// No x-staging in LDS: each thread loads its 3x18 strip directly from
// global (L1/L2-resident image), boundary handled via zero-page pointer
// select. LDS holds only wAll (per-ic combined weights, broadcast reads).
__global__ __launch_bounds__(256, 2) void conv_kernel(
    const float* __restrict__ x, const float* __restrict__ ka,
    const float* __restrict__ SW, float* __restrict__ zp,
    float* __restrict__ out) {
  __shared__ __align__(16) float wAll[256 * 36];
  int t = threadIdx.x;
  int oc0 = blockIdx.x * 4;
  int b = blockIdx.y;

  // zero-page init (identical-value multi-block writes: benign)
  if (t < 64) ((float4*)zp)[t] = make_float4(0.f, 0.f, 0.f, 0.f);

  float att0 = 0.5f / (1.f + expf(-ka[b * 4 + 0]));
  float att1 = 0.5f / (1.f + expf(-ka[b * 4 + 1]));
  float att2 = 0.5f / (1.f + expf(-ka[b * 4 + 2]));
  float att3 = 0.5f / (1.f + expf(-ka[b * 4 + 3]));

  for (int idx = t; idx < 256 * 36; idx += 256) {
    int ic = idx / 36;
    int r = idx - ic * 36;
    int oci = r / 9;
    int rr = r - oci * 9;
    int dy = rr / 3, dx = rr - dy * 3;
    size_t base = (size_t)((oc0 + oci) * 3 + dy) * D1 + (ic * 3 + dx);
    wAll[idx] = att0 * SW[base] + att1 * SW[base + 589824] +
                att2 * SW[base + 2 * 589824] + att3 * SW[base + 3 * 589824];
  }
  __syncthreads();

  int row = t >> 2;            // output row 0..63
  int cq = (t & 3) << 4;       // column quarter base
  const float* xb = x + (size_t)b * NC * 4096;
  bool rv0 = (row >= 1), rv2 = (row <= 62);
  bool lv = (cq > 0), rgv = (cq < 48);
  int ro0 = (row - 1) * 64, ro1 = row * 64, ro2 = (row + 1) * 64;

  float acc[4][16];
#pragma unroll
  for (int o = 0; o < 4; ++o)
#pragma unroll
    for (int p = 0; p < 16; ++p) acc[o][p] = 0.f;

  float sA[3][18], sB[3][18];

#define LOAD_STRIP(S, IC)                                                   \
  {                                                                         \
    const float* base_ = xb + (size_t)(IC)*4096;                            \
    const float* r0_ = rv0 ? base_ + ro0 : zp;                              \
    const float* r1_ = base_ + ro1;                                         \
    const float* r2_ = rv2 ? base_ + ro2 : zp;                              \
    const float* rp_[3] = {r0_, r1_, r2_};                                  \
    _Pragma("unroll") for (int r_ = 0; r_ < 3; ++r_) {                      \
      const float* p_ = rp_[r_];                                            \
      const float* pl_ = ((r_ == 0 ? rv0 : (r_ == 2 ? rv2 : true)) && lv)   \
                             ? p_ + cq - 1                                  \
                             : zp;                                          \
      const float* pr_ = ((r_ == 0 ? rv0 : (r_ == 2 ? rv2 : true)) && rgv)  \
                             ? p_ + cq + 16                                 \
                             : zp;                                          \
      S[r_][0] = *pl_;                                                      \
      float4 q0_ = *(const float4*)(p_ + cq);                               \
      float4 q1_ = *(const float4*)(p_ + cq + 4);                           \
      float4 q2_ = *(const float4*)(p_ + cq + 8);                           \
      float4 q3_ = *(const float4*)(p_ + cq + 12);                          \
      S[r_][1] = q0_.x;  S[r_][2] = q0_.y;  S[r_][3] = q0_.z;               \
      S[r_][4] = q0_.w;  S[r_][5] = q1_.x;  S[r_][6] = q1_.y;               \
      S[r_][7] = q1_.z;  S[r_][8] = q1_.w;  S[r_][9] = q2_.x;               \
      S[r_][10] = q2_.y; S[r_][11] = q2_.z; S[r_][12] = q2_.w;              \
      S[r_][13] = q3_.x; S[r_][14] = q3_.y; S[r_][15] = q3_.z;              \
      S[r_][16] = q3_.w; S[r_][17] = *pr_;                                  \
    }                                                                       \
  }

#define DO_FMA(S, IC)                                                       \
  {                                                                         \
    float4 wv_[9];                                                          \
    _Pragma("unroll") for (int j_ = 0; j_ < 9; ++j_) wv_[j_] =              \
        ((const float4*)wAll)[(IC)*9 + j_];                                 \
    const float* w_ = (const float*)wv_;                                    \
    _Pragma("unroll") for (int px_ = 0; px_ < 16; ++px_) {                  \
      _Pragma("unroll") for (int o_ = 0; o_ < 4; ++o_) {                    \
        float s_ = acc[o_][px_];                                            \
        s_ = fmaf(w_[o_ * 9 + 0], S[0][px_], s_);                           \
        s_ = fmaf(w_[o_ * 9 + 1], S[0][px_ + 1], s_);                       \
        s_ = fmaf(w_[o_ * 9 + 2], S[0][px_ + 2], s_);                       \
        s_ = fmaf(w_[o_ * 9 + 3], S[1][px_], s_);                           \
        s_ = fmaf(w_[o_ * 9 + 4], S[1][px_ + 1], s_);                       \
        s_ = fmaf(w_[o_ * 9 + 5], S[1][px_ + 2], s_);                       \
        s_ = fmaf(w_[o_ * 9 + 6], S[2][px_], s_);                           \
        s_ = fmaf(w_[o_ * 9 + 7], S[2][px_ + 1], s_);                       \
        s_ = fmaf(w_[o_ * 9 + 8], S[2][px_ + 2], s_);                       \
        acc[o_][px_] = s_;                                                  \
      }                                                                     \
    }                                                                       \
  }

  LOAD_STRIP(sA, 0)
  for (int ic = 0; ic < NC; ic += 2) {
    LOAD_STRIP(sB, ic + 1)
    DO_FMA(sA, ic)
    if (ic + 2 < NC) LOAD_STRIP(sA, ic + 2)
    DO_FMA(sB, ic + 1)
  }

#pragma unroll
  for (int o = 0; o < 4; ++o) {
    size_t base = (((size_t)b * NC + oc0 + o) * 64 + row) * 64 + cq;
    float4* op = (float4*)(out + base);
    op[0] = make_float4(acc[o][0], acc[o][1], acc[o][2], acc[o][3]);
    op[1] = make_float4(acc[o][4], acc[o][5], acc[o][6], acc[o][7]);
    op[2] = make_float4(acc[o][8], acc[o][9], acc[o][10], acc[o][11]);
    op[3] = make_float4(acc[o][12], acc[o][13], acc[o][14], acc[o][15]);
  }
}

extern "C" void kernel_launch(void* const* d_in, const int* in_sizes, int n_in,
                              void* d_out, int out_size, void* d_ws,
                              size_t ws_size, hipStream_t stream) {
  const float* x = (const float*)d_in[0];
  const float* dw = (const float*)d_in[1];
  const float* ka = (const float*)d_in[2];
  const int* fh = (const int*)d_in[3];
  const int* fw = (const int*)d_in[4];
  float* out = (float*)d_out;
  float* bufA = (float*)d_ws;             // spec, later SW
  float* bufY = bufA + SPEC_FLOATS;       // stage-A output; zp after stage B

  hipLaunchKernelGGL(scatter_kernel, dim3(1155, KNUM), dim3(256), 0, stream,
                     dw, fh, fw, bufA);
  hipLaunchKernelGGL(stageA_kernel, dim3(7, 12, KNUM), dim3(256), 0, stream,
                     bufA, bufY);
  hipLaunchKernelGGL(stageB_kernel, dim3(6, 12, KNUM), dim3(256), 0, stream,
                     bufY, bufA);
  hipLaunchKernelGGL(conv_kernel, dim3(64, NB), dim3(256), 0, stream, x, ka,
                     bufA, bufY, out);
}

// Round 4
// 455.449 us; speedup vs baseline: 4.1839x; 4.1839x over previous
//
#include <hip/hip_runtime.h>
#include <math.h>

#define D1 768
#define D2R 385
#define NF 295680   // 768*385
#define KNUM 4
#define NB 8
#define NC 256

// ws layout (floats):
//   bufA [0 .. SPEC)      : scattered spectrum (4,768,385) complex; reused as SW (4,768,768) real
//   bufY [SPEC .. 2*SPEC) : stage-A output (4,768,385) complex; reused as wBF
//                           (8,9,16,256,16) bf16 = 9.44 MB after stage A is consumed
#define SPEC_FLOATS 2365440
#define TWOPI_768 0.008181230868723419f

typedef __attribute__((ext_vector_type(8))) short short8;
typedef __attribute__((ext_vector_type(16))) float f32x16;

static __device__ __forceinline__ unsigned int f2bf(float f) {
  unsigned int u = __float_as_uint(f);
  return (u + 0x7fffu + ((u >> 16) & 1u)) >> 16;  // RNE, no NaN inputs
}

// ---------------- scatter: dft_weight -> dense half-spectrum -------------
__global__ __launch_bounds__(256) void scatter_kernel(
    const float* __restrict__ dw, const int* __restrict__ fh,
    const int* __restrict__ fw, float* __restrict__ spec) {
  int i = blockIdx.x * 256 + threadIdx.x;  // grid.x = 1155 exact
  int k = blockIdx.y;
  const float2 v = ((const float2*)dw)[(size_t)k * NF + i];
  int h = fh[i], w = fw[i];
  ((float2*)spec)[((size_t)k * D1 + h) * D2R + w] = v;
}

// ---------------- stage A: complex ifft along axis 0 (length 768) --------
__global__ __launch_bounds__(256) void stageA_kernel(
    const float* __restrict__ spec, float* __restrict__ Y) {
  __shared__ float tw[768 * 2];      // twiddle table (cos,sin)
  __shared__ float Ss[32 * 64 * 2];  // [h][c] complex
  __shared__ float Es[32 * 64 * 2];  // [h][m] complex
  int t = threadIdx.x;
  int c0 = blockIdx.x * 64;
  int m0 = blockIdx.y * 64;
  int k = blockIdx.z;
  for (int i = t; i < 768; i += 256) {
    float s, c;
    sincosf((float)i * TWOPI_768, &s, &c);
    ((float2*)tw)[i] = make_float2(c, s);
  }
  int tx = t & 31, ty = t >> 5;
  float ar0[8] = {}, ai0[8] = {}, ar1[8] = {}, ai1[8] = {};

  for (int kt = 0; kt < 24; ++kt) {
    int h0 = kt * 32;
    __syncthreads();
#pragma unroll
    for (int p = 0; p < 8; ++p) {  // S tile 32h x 64c
      int idx = t + 256 * p;
      int h = idx >> 6, c = idx & 63;
      float2 v = make_float2(0.f, 0.f);
      if (c0 + c < D2R)
        v = ((const float2*)spec)[((size_t)k * D1 + h0 + h) * D2R + c0 + c];
      ((float2*)Ss)[h * 64 + c] = v;
    }
#pragma unroll
    for (int p = 0; p < 8; ++p) {  // E tile 32h x 64m from table
      int idx = t + 256 * p;
      int h = idx >> 6, m = idx & 63;
      int tt = ((h0 + h) * (m0 + m)) % 768;
      ((float2*)Es)[h * 64 + m] = ((const float2*)tw)[tt];
    }
    __syncthreads();
#pragma unroll 2
    for (int h = 0; h < 32; ++h) {
      float2 S0 = ((float2*)Ss)[h * 64 + tx];
      float2 S1 = ((float2*)Ss)[h * 64 + tx + 32];
#pragma unroll
      for (int j = 0; j < 8; ++j) {
        float2 E = ((float2*)Es)[h * 64 + ty + 8 * j];
        ar0[j] = fmaf(S0.x, E.x, ar0[j]); ar0[j] = fmaf(-S0.y, E.y, ar0[j]);
        ai0[j] = fmaf(S0.x, E.y, ai0[j]); ai0[j] = fmaf(S0.y, E.x, ai0[j]);
        ar1[j] = fmaf(S1.x, E.x, ar1[j]); ar1[j] = fmaf(-S1.y, E.y, ar1[j]);
        ai1[j] = fmaf(S1.x, E.y, ai1[j]); ai1[j] = fmaf(S1.y, E.x, ai1[j]);
      }
    }
  }
#pragma unroll
  for (int q = 0; q < 2; ++q) {
    int c = c0 + tx + 32 * q;
    if (c < D2R) {
      float scale = (c == 0 || c == D2R - 1) ? 1.6954210069444445e-6f
                                             : 3.390842013888889e-6f;
      float* ar = q ? ar1 : ar0;
      float* ai = q ? ai1 : ai0;
#pragma unroll
      for (int j = 0; j < 8; ++j) {
        int m = m0 + ty + 8 * j;
        ((float2*)Y)[((size_t)k * D1 + m) * D2R + c] =
            make_float2(ar[j] * scale, ai[j] * scale);
      }
    }
  }
}

// ---------------- stage B: real irfft along axis 1 (385 -> 768) ----------
__global__ __launch_bounds__(256) void stageB_kernel(
    const float* __restrict__ Y, float* __restrict__ SW) {
  __shared__ float tw[768 * 2];
  __shared__ float Ys[32 * 65 * 2];   // [c][m] complex, padded
  __shared__ float Tt[32 * 128 * 2];  // [c][n] (cos,sin)
  int t = threadIdx.x;
  int n0 = blockIdx.x * 128;
  int m0 = blockIdx.y * 64;
  int k = blockIdx.z;
  for (int i = t; i < 768; i += 256) {
    float s, c;
    sincosf((float)i * TWOPI_768, &s, &c);
    ((float2*)tw)[i] = make_float2(c, s);
  }
  int tx = t & 31, ty = t >> 5;
  float acc[4][8] = {};

  for (int kt = 0; kt < 13; ++kt) {
    int cb = kt * 32;
    __syncthreads();
#pragma unroll
    for (int p = 0; p < 8; ++p) {  // Y tile transposed [c][m]
      int idx = t + 256 * p;
      int m = idx >> 5, c = idx & 31;
      float2 v = make_float2(0.f, 0.f);
      if (cb + c < D2R)
        v = ((const float2*)Y)[((size_t)k * D1 + m0 + m) * D2R + cb + c];
      ((float2*)Ys)[c * 65 + m] = v;
    }
#pragma unroll
    for (int p = 0; p < 16; ++p) {  // T tile 32c x 128n from table
      int idx = t + 256 * p;
      int c = idx >> 7, n = idx & 127;
      int tt = ((cb + c) * (n0 + n)) % 768;
      ((float2*)Tt)[c * 128 + n] = ((const float2*)tw)[tt];
    }
    __syncthreads();
#pragma unroll 2
    for (int c = 0; c < 32; ++c) {
      float2 T0 = ((float2*)Tt)[c * 128 + tx];
      float2 T1 = ((float2*)Tt)[c * 128 + tx + 32];
      float2 T2 = ((float2*)Tt)[c * 128 + tx + 64];
      float2 T3 = ((float2*)Tt)[c * 128 + tx + 96];
#pragma unroll
      for (int j = 0; j < 8; ++j) {
        float2 Yv = ((float2*)Ys)[c * 65 + ty + 8 * j];
        acc[0][j] = fmaf(Yv.x, T0.x, acc[0][j]);
        acc[0][j] = fmaf(-Yv.y, T0.y, acc[0][j]);
        acc[1][j] = fmaf(Yv.x, T1.x, acc[1][j]);
        acc[1][j] = fmaf(-Yv.y, T1.y, acc[1][j]);
        acc[2][j] = fmaf(Yv.x, T2.x, acc[2][j]);
        acc[2][j] = fmaf(-Yv.y, T2.y, acc[2][j]);
        acc[3][j] = fmaf(Yv.x, T3.x, acc[3][j]);
        acc[3][j] = fmaf(-Yv.y, T3.y, acc[3][j]);
      }
    }
  }
#pragma unroll
  for (int j = 0; j < 8; ++j) {
    int m = m0 + ty + 8 * j;
    size_t base = ((size_t)k * D1 + m) * D1 + n0 + tx;
#pragma unroll
    for (int q = 0; q < 4; ++q) SW[base + 32 * q] = acc[q][j];
  }
}

// ---------------- wprep: att-combine + bf16 + MFMA-friendly layout -------
// wBF[b][s=dy*3+dx][icb][oc][ici] = bf16( sum_k att[b,k]*SW[k][oc*3+dy][(icb*16+ici)*3+dx] )
__global__ __launch_bounds__(256) void wprep_kernel(
    const float* __restrict__ ka, const float* __restrict__ SW,
    unsigned short* __restrict__ wBF) {
  int task = blockIdx.x * 256 + threadIdx.x;  // grid 1152 -> 294912 tasks
  int oc = task & 255;
  int rest = task >> 8;
  int icb = rest & 15;
  int bs = rest >> 4;
  int s = bs % 9;
  int b = bs / 9;
  int dy = s / 3, dx = s - dy * 3;
  float a0 = 0.5f / (1.f + expf(-ka[b * 4 + 0]));
  float a1 = 0.5f / (1.f + expf(-ka[b * 4 + 1]));
  float a2 = 0.5f / (1.f + expf(-ka[b * 4 + 2]));
  float a3 = 0.5f / (1.f + expf(-ka[b * 4 + 3]));
  const float* r0 = SW + ((size_t)(oc * 3 + dy)) * D1 + icb * 48 + dx;
  const float* r1 = r0 + 589824;
  const float* r2 = r1 + 589824;
  const float* r3 = r2 + 589824;
  unsigned short ov[16];
#pragma unroll
  for (int i = 0; i < 16; ++i) {
    float v = a0 * r0[i * 3] + a1 * r1[i * 3] + a2 * r2[i * 3] + a3 * r3[i * 3];
    ov[i] = (unsigned short)f2bf(v);
  }
  uint4* dst = (uint4*)(wBF + (size_t)task * 16);
  dst[0] = *(uint4*)&ov[0];
  dst[1] = *(uint4*)&ov[8];
}

// ---------------- conv: bf16 MFMA implicit GEMM --------------------------
// Block: 128 oc x 128 px (2 image rows). 4 waves, each 64oc x 64px via
// 2x2 v_mfma_f32_32x32x16_bf16 accumulators. K = 16 icb x (16 ic x 9 shifts).
// LDS: xs [4 rows][66 cols][16 ic] bf16 (48B/site: aligned b128 B-frags,
// bank-spread staging); As [9][128 oc][16 ic] bf16.
#define XS_BYTES 12672  // 4*66*48
__global__ __launch_bounds__(256, 2) void conv_mfma_kernel(
    const float* __restrict__ x, const unsigned short* __restrict__ wBF,
    float* __restrict__ out) {
  __shared__ __align__(16) unsigned char lds[XS_BYTES + 36864];
  unsigned char* ldsX = lds;
  unsigned char* ldsA = lds + XS_BYTES;
  int t = threadIdx.x;
  int pxt = blockIdx.x, oct = blockIdx.y, b = blockIdx.z;
  int py0 = pxt * 2;
  int oc0 = oct * 128;
  int lane = t & 63, w = t >> 6;
  int ocq = w >> 1, pxq = w & 1;
  int n = lane & 31, half = lane >> 5;

  // zero halo cols (c=0 and c=65, rows 0..3) once; never overwritten
  if (t < 96) {
    int site = t / 12, word = t - site * 12;
    int r = site >> 1, c = (site & 1) ? 65 : 0;
    *(unsigned int*)(ldsX + (r * 66 + c) * 48 + word * 4) = 0u;
  }

  f32x16 acc[2][2];
#pragma unroll
  for (int i = 0; i < 2; ++i)
#pragma unroll
    for (int j = 0; j < 2; ++j)
#pragma unroll
      for (int r = 0; r < 16; ++r) acc[i][j][r] = 0.f;

  // x staging role: thread covers (icpair, row, 8 cols)
  int s_cq = t >> 5, s_r = (t >> 3) & 3, s_icp = t & 7;
  int iy = py0 - 1 + s_r;
  bool valid = (iy >= 0 && iy < 64);
  const float* xpb =
      x + (((size_t)b * NC) * 64 + (valid ? iy : 0)) * 64 + s_cq * 8;
  unsigned char* xw = ldsX + (s_r * 66 + 1 + s_cq * 8) * 48 + s_icp * 4;

  // A staging role: thread covers (oc, 8-ic half)
  int a_oc = t >> 1, a_hf = t & 1;
  const uint4* wg4 = (const uint4*)wBF;

  for (int icb = 0; icb < 16; ++icb) {
    __syncthreads();
    // ---- stage x tile ----
    {
      int ic = icb * 16 + s_icp * 2;
      float4 qa0 = make_float4(0.f, 0.f, 0.f, 0.f), qa1 = qa0, qb0 = qa0,
             qb1 = qa0;
      if (valid) {
        const float* p0 = xpb + (size_t)ic * 4096;
        qa0 = *(const float4*)p0;
        qa1 = *(const float4*)(p0 + 4);
        qb0 = *(const float4*)(p0 + 4096);
        qb1 = *(const float4*)(p0 + 4100);
      }
      float av[8] = {qa0.x, qa0.y, qa0.z, qa0.w, qa1.x, qa1.y, qa1.z, qa1.w};
      float bv[8] = {qb0.x, qb0.y, qb0.z, qb0.w, qb1.x, qb1.y, qb1.z, qb1.w};
#pragma unroll
      for (int j = 0; j < 8; ++j)
        *(unsigned int*)(xw + j * 48) = f2bf(av[j]) | (f2bf(bv[j]) << 16);
    }
    // ---- stage A tiles (all 9 shifts) ----
    {
      size_t base4 =
          ((size_t)(b * 9) * 16 + icb) * 512 + (size_t)(oc0 + a_oc) * 2 + a_hf;
      unsigned char* ap = ldsA + a_oc * 32 + a_hf * 16;
#pragma unroll
      for (int s = 0; s < 9; ++s)
        *(uint4*)(ap + s * 4096) = wg4[base4 + (size_t)s * 8192];
    }
    __syncthreads();
    // ---- compute: 9 shifts x 4 mfma ----
#pragma unroll
    for (int s = 0; s < 9; ++s) {
      int dy = s / 3, dx = s - (s / 3) * 3;
      const unsigned char* ab = ldsA + (s * 128 + ocq * 64 + n) * 32 + half * 16;
      short8 A0 = *(const short8*)ab;
      short8 A1 = *(const short8*)(ab + 32 * 32);
      const unsigned char* bb =
          ldsX + ((pxq + dy) * 66 + n + dx) * 48 + half * 16;
      short8 B0 = *(const short8*)bb;
      short8 B1 = *(const short8*)(bb + 32 * 48);
      acc[0][0] = __builtin_amdgcn_mfma_f32_32x32x16_bf16(A0, B0, acc[0][0], 0, 0, 0);
      acc[0][1] = __builtin_amdgcn_mfma_f32_32x32x16_bf16(A0, B1, acc[0][1], 0, 0, 0);
      acc[1][0] = __builtin_amdgcn_mfma_f32_32x32x16_bf16(A1, B0, acc[1][0], 0, 0, 0);
      acc[1][1] = __builtin_amdgcn_mfma_f32_32x32x16_bf16(A1, B1, acc[1][1], 0, 0, 0);
    }
  }

  // ---- epilogue: C/D layout col=lane&31(px), row=(reg&3)+8*(reg>>2)+4*half (oc)
  int py = py0 + pxq;
#pragma unroll
  for (int osub = 0; osub < 2; ++osub)
#pragma unroll
    for (int psub = 0; psub < 2; ++psub) {
      int OC = oc0 + ocq * 64 + osub * 32 + 4 * half;
      int pxc = psub * 32 + n;
      float* op = out + (((size_t)(b * NC + OC)) * 64 + py) * 64 + pxc;
#pragma unroll
      for (int reg = 0; reg < 16; ++reg) {
        int ocm = (reg & 3) + 8 * (reg >> 2);
        op[(size_t)ocm * 4096] = acc[osub][psub][reg];
      }
    }
}

extern "C" void kernel_launch(void* const* d_in, const int* in_sizes, int n_in,
                              void* d_out, int out_size, void* d_ws,
                              size_t ws_size, hipStream_t stream) {
  const float* x = (const float*)d_in[0];
  const float* dw = (const float*)d_in[1];
  const float* ka = (const float*)d_in[2];
  const int* fh = (const int*)d_in[3];
  const int* fw = (const int*)d_in[4];
  float* out = (float*)d_out;
  float* bufA = (float*)d_ws;             // spec, later SW
  float* bufY = bufA + SPEC_FLOATS;       // stage-A out, later wBF
  unsigned short* wBF = (unsigned short*)bufY;

  hipLaunchKernelGGL(scatter_kernel, dim3(1155, KNUM), dim3(256), 0, stream,
                     dw, fh, fw, bufA);
  hipLaunchKernelGGL(stageA_kernel, dim3(7, 12, KNUM), dim3(256), 0, stream,
                     bufA, bufY);
  hipLaunchKernelGGL(stageB_kernel, dim3(6, 12, KNUM), dim3(256), 0, stream,
                     bufY, bufA);
  hipLaunchKernelGGL(wprep_kernel, dim3(1152), dim3(256), 0, stream, ka, bufA,
                     wBF);
  hipLaunchKernelGGL(conv_mfma_kernel, dim3(32, 2, NB), dim3(256), 0, stream,
                     x, wBF, out);
}

// Round 5
// 234.762 us; speedup vs baseline: 8.1170x; 1.9400x over previous
//
#include <hip/hip_runtime.h>
#include <math.h>

#define D1 768
#define D2R 385
#define NF 295680   // 768*385
#define KNUM 4
#define NB 8
#define NC 256
#define TWOPI_768 0.008181230868723419f

// ---------------- ws layout (bytes) --------------------------------------
// specB  bf16 [4][448 c-rows][1536 k]   @ 0          (6,291,456 B)  B^T stage A
// Atw    bf16 [2][768 m][1536 k]        @ 6,291,456  (4,718,592 B)  A stage A
// Ya     bf16 [4][768 m][800 k]         @ 11,010,048 (4,915,200 B)  A stage B
// T      bf16 [768 n][800 k]            @ 15,925,248 (1,228,800 B)  B^T stage B
// SW     f32  [4][768][768]             @ 0          (9,437,184 B)  overlays specB+Atw (dead)
// wBF    bf16 [8][9][16][256][16]       @ 9,437,184  (9,437,184 B)  overlays Ya+T (dead)
// total 18,874,368 B  (<= 18,923,520 previously used)
#define ATW_U32 1572864u   // uint index of Atw
#define YA_U32 2752512u
#define T_U32 3981312u
#define SPECB_K_U32 344064u  // 448*768 uints per k
#define WBF_BYTE 9437184u

typedef __attribute__((ext_vector_type(8))) short short8;
typedef __attribute__((ext_vector_type(16))) float f32x16;
union U4S8 { unsigned int u[4]; short8 s8; };

static __device__ __forceinline__ unsigned int f2bf(float f) {
  unsigned int u = __float_as_uint(f);
  return (u + 0x7fffu + ((u >> 16) & 1u)) >> 16;  // RNE, no NaN inputs
}

// ---------------- prep: twiddle matrices + zero pads ---------------------
__global__ __launch_bounds__(256) void prep_kernel(unsigned int* ws) {
  long i = (long)blockIdx.x * 256 + threadIdx.x;  // grid 6744 -> 1,726,464 exact
  if (i < 1179648) {  // Atw: A_re/A_im [768 m][1536 k=2h], packed pairs
    int ri = (int)(i / 589824);
    int rem = (int)(i - (long)ri * 589824);
    int m = rem / 768, h = rem - (rem / 768) * 768;
    int idx = (h * m) % 768;
    float s, c;
    sincosf((float)idx * TWOPI_768, &s, &c);
    unsigned lo, hi;
    if (ri == 0) { lo = f2bf(c); hi = f2bf(-s); }
    else         { lo = f2bf(s); hi = f2bf(c); }
    ws[ATW_U32 + i] = lo | (hi << 16);
  } else if (i < 1486848) {  // T^T [768 n][800 k=2c], scale+Hermitian folded
    long j = i - 1179648;
    int n = (int)(j / 400), cc = (int)(j - (j / 400) * 400);
    unsigned v = 0;
    if (cc <= 384) {
      float wgt = (cc == 0 || cc == 384) ? 1.6954210069444445e-6f
                                         : 3.390842013888889e-6f;
      int idx = (cc * n) % 768;
      float s, c;
      sincosf((float)idx * TWOPI_768, &s, &c);
      v = f2bf(wgt * c) | (f2bf(-wgt * s) << 16);
    }
    ws[T_U32 + (size_t)n * 400 + cc] = v;
  } else if (i < 1680384) {  // specB zero rows 385..447
    long p = i - 1486848;
    int k = (int)(p / 48384);
    long r = p - (long)k * 48384;
    int row = 385 + (int)(r / 768);
    int col = (int)(r - (r / 768) * 768);
    ws[(size_t)k * SPECB_K_U32 + (size_t)row * 768 + col] = 0u;
  } else if (i < 1726464) {  // Ya zero cols 770..799
    long p = i - 1680384;
    int k = (int)(p / 11520);
    long r = p - (long)k * 11520;
    int m = (int)(r / 15), j = (int)(r - (r / 15) * 15);
    ws[YA_U32 + (size_t)k * 307200 + (size_t)m * 400 + 385 + j] = 0u;
  }
}

// ---------------- scatter: dft_weight -> bf16 B^T spectrum ---------------
__global__ __launch_bounds__(256) void scatter_kernel(
    const float* __restrict__ dw, const int* __restrict__ fh,
    const int* __restrict__ fw, unsigned int* __restrict__ specB) {
  int i = blockIdx.x * 256 + threadIdx.x;  // grid.x = 1155 exact
  int k = blockIdx.y;
  const float2 v = ((const float2*)dw)[(size_t)k * NF + i];
  int h = fh[i], c = fw[i];
  specB[(size_t)k * SPECB_K_U32 + (size_t)c * 768 + h] =
      f2bf(v.x) | (f2bf(v.y) << 16);
}

// ---------------- fftA: bf16 MFMA GEMM, M=768 N=448(385) K=1536 ----------
// C[m][c] = sum_k Atw[ri][m][k] * specB[kk][c][k];  write Ya[m][2c+ri] bf16
__global__ __launch_bounds__(256) void fftA_kernel(
    const unsigned short* __restrict__ Atw,
    const unsigned short* __restrict__ specB,
    unsigned short* __restrict__ Ya) {
  __shared__ unsigned short Al[64 * 36], Bl[64 * 36];  // 72B rows (pad 8B)
  int t = threadIdx.x;
  int mt = blockIdx.x, nt = blockIdx.y, z = blockIdx.z;
  int ri = z & 1, k = z >> 1;
  const unsigned short* Ag =
      Atw + (size_t)ri * 1179648 + (size_t)(mt * 64) * 1536;
  const unsigned short* Bg =
      specB + (size_t)k * 688128 + (size_t)(nt * 64) * 1536;
  int rowS = t >> 2, q = t & 3;
  int lane = t & 63, w = t >> 6;
  int moff = (w & 1) * 32, noff = (w >> 1) * 32;
  int lm = lane & 31, half = lane >> 5;

  f32x16 acc;
#pragma unroll
  for (int r = 0; r < 16; ++r) acc[r] = 0.f;

  for (int kb = 0; kb < 48; ++kb) {
    uint4 av = *(const uint4*)(Ag + (size_t)rowS * 1536 + kb * 32 + q * 8);
    uint4 bv = *(const uint4*)(Bg + (size_t)rowS * 1536 + kb * 32 + q * 8);
    __syncthreads();
    int wr = rowS * 36 + q * 8;
    *(uint2*)&Al[wr] = make_uint2(av.x, av.y);
    *(uint2*)&Al[wr + 4] = make_uint2(av.z, av.w);
    *(uint2*)&Bl[wr] = make_uint2(bv.x, bv.y);
    *(uint2*)&Bl[wr + 4] = make_uint2(bv.z, bv.w);
    __syncthreads();
#pragma unroll
    for (int kk2 = 0; kk2 < 2; ++kk2) {
      int ab = (moff + lm) * 36 + kk2 * 16 + half * 8;
      int bb = (noff + lm) * 36 + kk2 * 16 + half * 8;
      U4S8 ua, ub;
      *(uint2*)&ua.u[0] = *(const uint2*)&Al[ab];
      *(uint2*)&ua.u[2] = *(const uint2*)&Al[ab + 4];
      *(uint2*)&ub.u[0] = *(const uint2*)&Bl[bb];
      *(uint2*)&ub.u[2] = *(const uint2*)&Bl[bb + 4];
      acc = __builtin_amdgcn_mfma_f32_32x32x16_bf16(ua.s8, ub.s8, acc, 0, 0, 0);
    }
  }

  int c = nt * 64 + noff + lm;
  if (c < D2R) {
    unsigned short* Yk = Ya + (size_t)k * 614400;
    int mb = mt * 64 + moff + 4 * half;
#pragma unroll
    for (int reg = 0; reg < 16; ++reg) {
      int m = mb + (reg & 3) + 8 * (reg >> 2);
      Yk[(size_t)m * 800 + 2 * c + ri] = (unsigned short)f2bf(acc[reg]);
    }
  }
}

// ---------------- fftB: bf16 MFMA GEMM, M=768 N=768 K=800 ----------------
// SW[m][n] = sum_k Ya[m][k] * T[n][k]   (fp32 out)
__global__ __launch_bounds__(256) void fftB_kernel(
    const unsigned short* __restrict__ Ya, const unsigned short* __restrict__ T,
    float* __restrict__ SW) {
  __shared__ unsigned short Al[64 * 36], Bl[64 * 36];
  int t = threadIdx.x;
  int mt = blockIdx.x, nt = blockIdx.y, k = blockIdx.z;
  const unsigned short* Ag = Ya + (size_t)k * 614400 + (size_t)(mt * 64) * 800;
  const unsigned short* Bg = T + (size_t)(nt * 64) * 800;
  int rowS = t >> 2, q = t & 3;
  int lane = t & 63, w = t >> 6;
  int moff = (w & 1) * 32, noff = (w >> 1) * 32;
  int lm = lane & 31, half = lane >> 5;

  f32x16 acc;
#pragma unroll
  for (int r = 0; r < 16; ++r) acc[r] = 0.f;

  for (int kb = 0; kb < 25; ++kb) {
    uint4 av = *(const uint4*)(Ag + (size_t)rowS * 800 + kb * 32 + q * 8);
    uint4 bv = *(const uint4*)(Bg + (size_t)rowS * 800 + kb * 32 + q * 8);
    __syncthreads();
    int wr = rowS * 36 + q * 8;
    *(uint2*)&Al[wr] = make_uint2(av.x, av.y);
    *(uint2*)&Al[wr + 4] = make_uint2(av.z, av.w);
    *(uint2*)&Bl[wr] = make_uint2(bv.x, bv.y);
    *(uint2*)&Bl[wr + 4] = make_uint2(bv.z, bv.w);
    __syncthreads();
#pragma unroll
    for (int kk2 = 0; kk2 < 2; ++kk2) {
      int ab = (moff + lm) * 36 + kk2 * 16 + half * 8;
      int bb = (noff + lm) * 36 + kk2 * 16 + half * 8;
      U4S8 ua, ub;
      *(uint2*)&ua.u[0] = *(const uint2*)&Al[ab];
      *(uint2*)&ua.u[2] = *(const uint2*)&Al[ab + 4];
      *(uint2*)&ub.u[0] = *(const uint2*)&Bl[bb];
      *(uint2*)&ub.u[2] = *(const uint2*)&Bl[bb + 4];
      acc = __builtin_amdgcn_mfma_f32_32x32x16_bf16(ua.s8, ub.s8, acc, 0, 0, 0);
    }
  }

  float* SWk = SW + (size_t)k * 589824;
  int n = nt * 64 + noff + lm;
  int mb = mt * 64 + moff + 4 * half;
#pragma unroll
  for (int reg = 0; reg < 16; ++reg) {
    int m = mb + (reg & 3) + 8 * (reg >> 2);
    SWk[(size_t)m * 768 + n] = acc[reg];
  }
}

// ---------------- wprep: att-combine + bf16 + MFMA-friendly layout -------
__global__ __launch_bounds__(256) void wprep_kernel(
    const float* __restrict__ ka, const float* __restrict__ SW,
    unsigned short* __restrict__ wBF) {
  int task = blockIdx.x * 256 + threadIdx.x;  // grid 1152
  int oc = task & 255;
  int rest = task >> 8;
  int icb = rest & 15;
  int bs = rest >> 4;
  int s = bs % 9;
  int b = bs / 9;
  int dy = s / 3, dx = s - dy * 3;
  float a0 = 0.5f / (1.f + expf(-ka[b * 4 + 0]));
  float a1 = 0.5f / (1.f + expf(-ka[b * 4 + 1]));
  float a2 = 0.5f / (1.f + expf(-ka[b * 4 + 2]));
  float a3 = 0.5f / (1.f + expf(-ka[b * 4 + 3]));
  const float* r0 = SW + ((size_t)(oc * 3 + dy)) * D1 + icb * 48 + dx;
  const float* r1 = r0 + 589824;
  const float* r2 = r1 + 589824;
  const float* r3 = r2 + 589824;
  unsigned short ov[16];
#pragma unroll
  for (int i = 0; i < 16; ++i) {
    float v = a0 * r0[i * 3] + a1 * r1[i * 3] + a2 * r2[i * 3] + a3 * r3[i * 3];
    ov[i] = (unsigned short)f2bf(v);
  }
  uint4* dst = (uint4*)(wBF + (size_t)task * 16);
  dst[0] = *(uint4*)&ov[0];
  dst[1] = *(uint4*)&ov[8];
}

// ---------------- conv: bf16 MFMA implicit GEMM (unchanged from R4) ------
#define XS_BYTES 12672  // 4*66*48
__global__ __launch_bounds__(256, 2) void conv_mfma_kernel(
    const float* __restrict__ x, const unsigned short* __restrict__ wBF,
    float* __restrict__ out) {
  __shared__ __align__(16) unsigned char lds[XS_BYTES + 36864];
  unsigned char* ldsX = lds;
  unsigned char* ldsA = lds + XS_BYTES;
  int t = threadIdx.x;
  int pxt = blockIdx.x, oct = blockIdx.y, b = blockIdx.z;
  int py0 = pxt * 2;
  int oc0 = oct * 128;
  int lane = t & 63, w = t >> 6;
  int ocq = w >> 1, pxq = w & 1;
  int n = lane & 31, half = lane >> 5;

  if (t < 96) {
    int site = t / 12, word = t - site * 12;
    int r = site >> 1, c = (site & 1) ? 65 : 0;
    *(unsigned int*)(ldsX + (r * 66 + c) * 48 + word * 4) = 0u;
  }

  f32x16 acc[2][2];
#pragma unroll
  for (int i = 0; i < 2; ++i)
#pragma unroll
    for (int j = 0; j < 2; ++j)
#pragma unroll
      for (int r = 0; r < 16; ++r) acc[i][j][r] = 0.f;

  int s_cq = t >> 5, s_r = (t >> 3) & 3, s_icp = t & 7;
  int iy = py0 - 1 + s_r;
  bool valid = (iy >= 0 && iy < 64);
  const float* xpb =
      x + (((size_t)b * NC) * 64 + (valid ? iy : 0)) * 64 + s_cq * 8;
  unsigned char* xw = ldsX + (s_r * 66 + 1 + s_cq * 8) * 48 + s_icp * 4;

  int a_oc = t >> 1, a_hf = t & 1;
  const uint4* wg4 = (const uint4*)wBF;

  for (int icb = 0; icb < 16; ++icb) {
    __syncthreads();
    {
      int ic = icb * 16 + s_icp * 2;
      float4 qa0 = make_float4(0.f, 0.f, 0.f, 0.f), qa1 = qa0, qb0 = qa0,
             qb1 = qa0;
      if (valid) {
        const float* p0 = xpb + (size_t)ic * 4096;
        qa0 = *(const float4*)p0;
        qa1 = *(const float4*)(p0 + 4);
        qb0 = *(const float4*)(p0 + 4096);
        qb1 = *(const float4*)(p0 + 4100);
      }
      float av[8] = {qa0.x, qa0.y, qa0.z, qa0.w, qa1.x, qa1.y, qa1.z, qa1.w};
      float bv[8] = {qb0.x, qb0.y, qb0.z, qb0.w, qb1.x, qb1.y, qb1.z, qb1.w};
#pragma unroll
      for (int j = 0; j < 8; ++j)
        *(unsigned int*)(xw + j * 48) = f2bf(av[j]) | (f2bf(bv[j]) << 16);
    }
    {
      size_t base4 =
          ((size_t)(b * 9) * 16 + icb) * 512 + (size_t)(oc0 + a_oc) * 2 + a_hf;
      unsigned char* ap = ldsA + a_oc * 32 + a_hf * 16;
#pragma unroll
      for (int s = 0; s < 9; ++s)
        *(uint4*)(ap + s * 4096) = wg4[base4 + (size_t)s * 8192];
    }
    __syncthreads();
#pragma unroll
    for (int s = 0; s < 9; ++s) {
      int dy = s / 3, dx = s - (s / 3) * 3;
      const unsigned char* ab = ldsA + (s * 128 + ocq * 64 + n) * 32 + half * 16;
      short8 A0 = *(const short8*)ab;
      short8 A1 = *(const short8*)(ab + 32 * 32);
      const unsigned char* bb =
          ldsX + ((pxq + dy) * 66 + n + dx) * 48 + half * 16;
      short8 B0 = *(const short8*)bb;
      short8 B1 = *(const short8*)(bb + 32 * 48);
      acc[0][0] = __builtin_amdgcn_mfma_f32_32x32x16_bf16(A0, B0, acc[0][0], 0, 0, 0);
      acc[0][1] = __builtin_amdgcn_mfma_f32_32x32x16_bf16(A0, B1, acc[0][1], 0, 0, 0);
      acc[1][0] = __builtin_amdgcn_mfma_f32_32x32x16_bf16(A1, B0, acc[1][0], 0, 0, 0);
      acc[1][1] = __builtin_amdgcn_mfma_f32_32x32x16_bf16(A1, B1, acc[1][1], 0, 0, 0);
    }
  }

  int py = py0 + pxq;
#pragma unroll
  for (int osub = 0; osub < 2; ++osub)
#pragma unroll
    for (int psub = 0; psub < 2; ++psub) {
      int OC = oc0 + ocq * 64 + osub * 32 + 4 * half;
      int pxc = psub * 32 + n;
      float* op = out + (((size_t)(b * NC + OC)) * 64 + py) * 64 + pxc;
#pragma unroll
      for (int reg = 0; reg < 16; ++reg) {
        int ocm = (reg & 3) + 8 * (reg >> 2);
        op[(size_t)ocm * 4096] = acc[osub][psub][reg];
      }
    }
}

extern "C" void kernel_launch(void* const* d_in, const int* in_sizes, int n_in,
                              void* d_out, int out_size, void* d_ws,
                              size_t ws_size, hipStream_t stream) {
  const float* x = (const float*)d_in[0];
  const float* dw = (const float*)d_in[1];
  const float* ka = (const float*)d_in[2];
  const int* fh = (const int*)d_in[3];
  const int* fw = (const int*)d_in[4];
  float* out = (float*)d_out;
  unsigned int* ws = (unsigned int*)d_ws;
  unsigned short* specB = (unsigned short*)d_ws;
  const unsigned short* Atw = (const unsigned short*)((char*)d_ws + 6291456);
  unsigned short* Ya = (unsigned short*)((char*)d_ws + 11010048);
  const unsigned short* T = (const unsigned short*)((char*)d_ws + 15925248);
  float* SW = (float*)d_ws;
  unsigned short* wBF = (unsigned short*)((char*)d_ws + WBF_BYTE);

  hipLaunchKernelGGL(prep_kernel, dim3(6744), dim3(256), 0, stream, ws);
  hipLaunchKernelGGL(scatter_kernel, dim3(1155, KNUM), dim3(256), 0, stream,
                     dw, fh, fw, (unsigned int*)specB);
  hipLaunchKernelGGL(fftA_kernel, dim3(12, 7, 8), dim3(256), 0, stream, Atw,
                     specB, Ya);
  hipLaunchKernelGGL(fftB_kernel, dim3(12, 12, KNUM), dim3(256), 0, stream, Ya,
                     T, SW);
  hipLaunchKernelGGL(wprep_kernel, dim3(1152), dim3(256), 0, stream, ka, SW,
                     wBF);
  hipLaunchKernelGGL(conv_mfma_kernel, dim3(32, 2, NB), dim3(256), 0, stream,
                     x, wBF, out);
}

// Round 6
// 221.198 us; speedup vs baseline: 8.6147x; 1.0613x over previous
//
#include <hip/hip_runtime.h>
#include <math.h>

#define D1 768
#define D2R 385
#define NF 295680   // 768*385
#define KNUM 4
#define NB 8
#define NC 256
#define TWOPI_768 0.008181230868723419f

// ---------------- ws layout (bytes) --------------------------------------
// specB  bf16 [4][448 c-rows][1536 k]   @ 0          (6,291,456 B)  B^T stage A
// Atw    bf16 [2][768 m][1536 k]        @ 6,291,456  (4,718,592 B)  A stage A
// Ya     bf16 [4][768 m][800 k]         @ 11,010,048 (4,915,200 B)  A stage B
// T      bf16 [768 n][800 k]            @ 15,925,248 (1,228,800 B)  B^T stage B
// SW     f32  [4][768][768]             @ 0          (9,437,184 B)  overlays specB+Atw (dead)
// wBF    bf16 [8][9][16][256][16]       @ 9,437,184  (9,437,184 B)  overlays Ya+T (dead)
#define ATW_U32 1572864u
#define YA_U32 2752512u
#define T_U32 3981312u
#define SPECB_K_U32 344064u  // 448*768 uints per k
#define WBF_BYTE 9437184u

typedef __attribute__((ext_vector_type(8))) short short8;
typedef __attribute__((ext_vector_type(16))) float f32x16;
union U4S8 { unsigned int u[4]; uint4 u4; short8 s8; };

static __device__ __forceinline__ unsigned int f2bf(float f) {
  unsigned int u = __float_as_uint(f);
  return (u + 0x7fffu + ((u >> 16) & 1u)) >> 16;  // RNE, no NaN inputs
}

// ---------------- prep: scatter + twiddle matrices + zero pads -----------
__global__ __launch_bounds__(256) void prep_kernel(
    const float* __restrict__ dw, const int* __restrict__ fh,
    const int* __restrict__ fw, unsigned int* __restrict__ ws) {
  long i = (long)blockIdx.x * 256 + threadIdx.x;  // grid 11364 -> 2,909,184
  if (i < 1182720) {  // scatter: dft_weight -> bf16 B^T spectrum
    int k = (int)(i / NF);
    int r = (int)(i - (long)k * NF);
    const float2 v = ((const float2*)dw)[i];
    int h = fh[r], c = fw[r];
    ws[(size_t)k * SPECB_K_U32 + (size_t)c * 768 + h] =
        f2bf(v.x) | (f2bf(v.y) << 16);
    return;
  }
  long j = i - 1182720;
  if (j < 1179648) {  // Atw: A_re/A_im [768 m][1536 k=2h], packed pairs
    int ri = (int)(j / 589824);
    int rem = (int)(j - (long)ri * 589824);
    int m = rem / 768, h = rem - (rem / 768) * 768;
    int idx = (h * m) % 768;
    float s, c;
    sincosf((float)idx * TWOPI_768, &s, &c);
    unsigned lo, hi;
    if (ri == 0) { lo = f2bf(c); hi = f2bf(-s); }
    else         { lo = f2bf(s); hi = f2bf(c); }
    ws[ATW_U32 + j] = lo | (hi << 16);
  } else if (j < 1486848) {  // T^T [768 n][800 k=2c], scale+Hermitian folded
    long p = j - 1179648;
    int n = (int)(p / 400), cc = (int)(p - (p / 400) * 400);
    unsigned v = 0;
    if (cc <= 384) {
      float wgt = (cc == 0 || cc == 384) ? 1.6954210069444445e-6f
                                         : 3.390842013888889e-6f;
      int idx = (cc * n) % 768;
      float s, c;
      sincosf((float)idx * TWOPI_768, &s, &c);
      v = f2bf(wgt * c) | (f2bf(-wgt * s) << 16);
    }
    ws[T_U32 + (size_t)n * 400 + cc] = v;
  } else if (j < 1680384) {  // specB zero rows 385..447
    long p = j - 1486848;
    int k = (int)(p / 48384);
    long r = p - (long)k * 48384;
    int row = 385 + (int)(r / 768);
    int col = (int)(r - (r / 768) * 768);
    ws[(size_t)k * SPECB_K_U32 + (size_t)row * 768 + col] = 0u;
  } else if (j < 1726464) {  // Ya zero cols 770..799
    long p = j - 1680384;
    int k = (int)(p / 11520);
    long r = p - (long)k * 11520;
    int m = (int)(r / 15), jj = (int)(r - (r / 15) * 15);
    ws[YA_U32 + (size_t)k * 307200 + (size_t)m * 400 + 385 + jj] = 0u;
  }
}

// ---------------- fftA: bf16 MFMA GEMM, M=768 N=448(385) K=1536 ----------
__global__ __launch_bounds__(256) void fftA_kernel(
    const unsigned short* __restrict__ Atw,
    const unsigned short* __restrict__ specB,
    unsigned short* __restrict__ Ya) {
  __shared__ unsigned short Al[64 * 36], Bl[64 * 36];  // 72B rows (pad 8B)
  int t = threadIdx.x;
  int mt = blockIdx.x, nt = blockIdx.y, z = blockIdx.z;
  int ri = z & 1, k = z >> 1;
  const unsigned short* Ag =
      Atw + (size_t)ri * 1179648 + (size_t)(mt * 64) * 1536;
  const unsigned short* Bg =
      specB + (size_t)k * 688128 + (size_t)(nt * 64) * 1536;
  int rowS = t >> 2, q = t & 3;
  int lane = t & 63, w = t >> 6;
  int moff = (w & 1) * 32, noff = (w >> 1) * 32;
  int lm = lane & 31, half = lane >> 5;

  f32x16 acc;
#pragma unroll
  for (int r = 0; r < 16; ++r) acc[r] = 0.f;

  for (int kb = 0; kb < 48; ++kb) {
    uint4 av = *(const uint4*)(Ag + (size_t)rowS * 1536 + kb * 32 + q * 8);
    uint4 bv = *(const uint4*)(Bg + (size_t)rowS * 1536 + kb * 32 + q * 8);
    __syncthreads();
    int wr = rowS * 36 + q * 8;
    *(uint2*)&Al[wr] = make_uint2(av.x, av.y);
    *(uint2*)&Al[wr + 4] = make_uint2(av.z, av.w);
    *(uint2*)&Bl[wr] = make_uint2(bv.x, bv.y);
    *(uint2*)&Bl[wr + 4] = make_uint2(bv.z, bv.w);
    __syncthreads();
#pragma unroll
    for (int kk2 = 0; kk2 < 2; ++kk2) {
      int ab = (moff + lm) * 36 + kk2 * 16 + half * 8;
      int bb = (noff + lm) * 36 + kk2 * 16 + half * 8;
      U4S8 ua, ub;
      *(uint2*)&ua.u[0] = *(const uint2*)&Al[ab];
      *(uint2*)&ua.u[2] = *(const uint2*)&Al[ab + 4];
      *(uint2*)&ub.u[0] = *(const uint2*)&Bl[bb];
      *(uint2*)&ub.u[2] = *(const uint2*)&Bl[bb + 4];
      acc = __builtin_amdgcn_mfma_f32_32x32x16_bf16(ua.s8, ub.s8, acc, 0, 0, 0);
    }
  }

  int c = nt * 64 + noff + lm;
  if (c < D2R) {
    unsigned short* Yk = Ya + (size_t)k * 614400;
    int mb = mt * 64 + moff + 4 * half;
#pragma unroll
    for (int reg = 0; reg < 16; ++reg) {
      int m = mb + (reg & 3) + 8 * (reg >> 2);
      Yk[(size_t)m * 800 + 2 * c + ri] = (unsigned short)f2bf(acc[reg]);
    }
  }
}

// ---------------- fftB: bf16 MFMA GEMM, M=768 N=768 K=800 ----------------
__global__ __launch_bounds__(256) void fftB_kernel(
    const unsigned short* __restrict__ Ya, const unsigned short* __restrict__ T,
    float* __restrict__ SW) {
  __shared__ unsigned short Al[64 * 36], Bl[64 * 36];
  int t = threadIdx.x;
  int mt = blockIdx.x, nt = blockIdx.y, k = blockIdx.z;
  const unsigned short* Ag = Ya + (size_t)k * 614400 + (size_t)(mt * 64) * 800;
  const unsigned short* Bg = T + (size_t)(nt * 64) * 800;
  int rowS = t >> 2, q = t & 3;
  int lane = t & 63, w = t >> 6;
  int moff = (w & 1) * 32, noff = (w >> 1) * 32;
  int lm = lane & 31, half = lane >> 5;

  f32x16 acc;
#pragma unroll
  for (int r = 0; r < 16; ++r) acc[r] = 0.f;

  for (int kb = 0; kb < 25; ++kb) {
    uint4 av = *(const uint4*)(Ag + (size_t)rowS * 800 + kb * 32 + q * 8);
    uint4 bv = *(const uint4*)(Bg + (size_t)rowS * 800 + kb * 32 + q * 8);
    __syncthreads();
    int wr = rowS * 36 + q * 8;
    *(uint2*)&Al[wr] = make_uint2(av.x, av.y);
    *(uint2*)&Al[wr + 4] = make_uint2(av.z, av.w);
    *(uint2*)&Bl[wr] = make_uint2(bv.x, bv.y);
    *(uint2*)&Bl[wr + 4] = make_uint2(bv.z, bv.w);
    __syncthreads();
#pragma unroll
    for (int kk2 = 0; kk2 < 2; ++kk2) {
      int ab = (moff + lm) * 36 + kk2 * 16 + half * 8;
      int bb = (noff + lm) * 36 + kk2 * 16 + half * 8;
      U4S8 ua, ub;
      *(uint2*)&ua.u[0] = *(const uint2*)&Al[ab];
      *(uint2*)&ua.u[2] = *(const uint2*)&Al[ab + 4];
      *(uint2*)&ub.u[0] = *(const uint2*)&Bl[bb];
      *(uint2*)&ub.u[2] = *(const uint2*)&Bl[bb + 4];
      acc = __builtin_amdgcn_mfma_f32_32x32x16_bf16(ua.s8, ub.s8, acc, 0, 0, 0);
    }
  }

  float* SWk = SW + (size_t)k * 589824;
  int n = nt * 64 + noff + lm;
  int mb = mt * 64 + moff + 4 * half;
#pragma unroll
  for (int reg = 0; reg < 16; ++reg) {
    int m = mb + (reg & 3) + 8 * (reg >> 2);
    SWk[(size_t)m * 768 + n] = acc[reg];
  }
}

// ---------------- wprep v2: b-loop inside -> SW reads /8 -----------------
// task = (s, icb, oc); writes wBF[b][s][icb][oc][ic16] for all 8 b
__global__ __launch_bounds__(256) void wprep_kernel(
    const float* __restrict__ ka, const float* __restrict__ SW,
    unsigned short* __restrict__ wBF) {
  int task = blockIdx.x * 256 + threadIdx.x;  // grid 144 -> 36864
  int oc = task & 255;
  int rest = task >> 8;   // 0..143
  int icb = rest & 15;
  int s = rest >> 4;      // 0..8
  int dy = s / 3, dx = s - dy * 3;

  float att[8][4];
#pragma unroll
  for (int b = 0; b < 8; ++b)
#pragma unroll
    for (int k = 0; k < 4; ++k)
      att[b][k] = 0.5f / (1.f + expf(-ka[b * 4 + k]));

  const float* r0 = SW + ((size_t)(oc * 3 + dy)) * D1 + icb * 48 + dx;
  const float* r1 = r0 + 589824;
  const float* r2 = r1 + 589824;
  const float* r3 = r2 + 589824;
  float v0[16], v1[16], v2[16], v3[16];
#pragma unroll
  for (int i = 0; i < 16; ++i) {
    v0[i] = r0[i * 3]; v1[i] = r1[i * 3];
    v2[i] = r2[i * 3]; v3[i] = r3[i * 3];
  }
#pragma unroll
  for (int b = 0; b < 8; ++b) {
    unsigned short ov[16];
#pragma unroll
    for (int i = 0; i < 16; ++i) {
      float v = att[b][0] * v0[i] + att[b][1] * v1[i] + att[b][2] * v2[i] +
                att[b][3] * v3[i];
      ov[i] = (unsigned short)f2bf(v);
    }
    uint4* dst =
        (uint4*)(wBF + ((((size_t)(b * 9 + s) * 16 + icb) * 256 + oc) * 16));
    dst[0] = *(uint4*)&ov[0];
    dst[1] = *(uint4*)&ov[8];
  }
}

// ---------------- conv v3: A direct-from-global, LDS holds only x --------
// Block 128oc x 128px (2 rows), 4 waves (ocq,pxq) each 64x64, 2x2 acc.
// Per s: A-frags prefetched from global wBF (L2), B-frags from LDS x tile.
__global__ __launch_bounds__(256, 2) void conv_mfma_kernel(
    const float* __restrict__ x, const unsigned short* __restrict__ wBF,
    float* __restrict__ out) {
  __shared__ __align__(16) unsigned char ldsX[4 * 66 * 48];  // 12672 B
  int t = threadIdx.x;
  int pxt = blockIdx.x, oct = blockIdx.y, b = blockIdx.z;
  int py0 = pxt * 2;
  int oc0 = oct * 128;
  int lane = t & 63, w = t >> 6;
  int ocq = w >> 1, pxq = w & 1;
  int n = lane & 31, half = lane >> 5;

  // zero halo cols (c=0 and c=65, rows 0..3) once
  if (t < 96) {
    int site = t / 12, word = t - site * 12;
    int r = site >> 1, c = (site & 1) ? 65 : 0;
    *(unsigned int*)(ldsX + (r * 66 + c) * 48 + word * 4) = 0u;
  }

  f32x16 acc[2][2];
#pragma unroll
  for (int i = 0; i < 2; ++i)
#pragma unroll
    for (int j = 0; j < 2; ++j)
#pragma unroll
      for (int r = 0; r < 16; ++r) acc[i][j][r] = 0.f;

  // x staging role
  int s_cq = t >> 5, s_r = (t >> 3) & 3, s_icp = t & 7;
  int iy = py0 - 1 + s_r;
  bool valid = (iy >= 0 && iy < 64);
  const float* xpb =
      x + (((size_t)b * NC) * 64 + (valid ? iy : 0)) * 64 + s_cq * 8;
  unsigned char* xw = ldsX + (s_r * 66 + 1 + s_cq * 8) * 48 + s_icp * 4;

  // A-frag addressing (uint4 units)
  const uint4* wg4 = (const uint4*)wBF;
  int laneoff = (oc0 + ocq * 64 + n) * 2 + half;

  U4S8 a0, a1, na0, na1;
  {
    size_t sb = ((size_t)(b * 9 + 0) * 16 + 0) * 512;
    a0.u4 = wg4[sb + laneoff];
    a1.u4 = wg4[sb + laneoff + 64];
  }

  for (int icb = 0; icb < 16; ++icb) {
    __syncthreads();
    {  // stage x tile (16 ic, 2 per thread)
      int ic = icb * 16 + s_icp * 2;
      float4 qa0 = make_float4(0.f, 0.f, 0.f, 0.f), qa1 = qa0, qb0 = qa0,
             qb1 = qa0;
      if (valid) {
        const float* p0 = xpb + (size_t)ic * 4096;
        qa0 = *(const float4*)p0;
        qa1 = *(const float4*)(p0 + 4);
        qb0 = *(const float4*)(p0 + 4096);
        qb1 = *(const float4*)(p0 + 4100);
      }
      float av[8] = {qa0.x, qa0.y, qa0.z, qa0.w, qa1.x, qa1.y, qa1.z, qa1.w};
      float bv[8] = {qb0.x, qb0.y, qb0.z, qb0.w, qb1.x, qb1.y, qb1.z, qb1.w};
#pragma unroll
      for (int j = 0; j < 8; ++j)
        *(unsigned int*)(xw + j * 48) = f2bf(av[j]) | (f2bf(bv[j]) << 16);
    }
    __syncthreads();
#pragma unroll
    for (int s = 0; s < 9; ++s) {
      // prefetch next step's A frags (independent of LDS)
      bool pf = !(icb == 15 && s == 8);
      int ns = (s == 8) ? 0 : s + 1;
      int nicb = (s == 8) ? icb + 1 : icb;
      if (pf) {
        size_t sb = ((size_t)(b * 9 + ns) * 16 + nicb) * 512;
        na0.u4 = wg4[sb + laneoff];
        na1.u4 = wg4[sb + laneoff + 64];
      }
      int dy = s / 3, dx = s - dy * 3;
      const unsigned char* bb =
          ldsX + ((pxq + dy) * 66 + n + dx) * 48 + half * 16;
      short8 B0 = *(const short8*)bb;
      short8 B1 = *(const short8*)(bb + 32 * 48);
      acc[0][0] = __builtin_amdgcn_mfma_f32_32x32x16_bf16(a0.s8, B0, acc[0][0], 0, 0, 0);
      acc[0][1] = __builtin_amdgcn_mfma_f32_32x32x16_bf16(a0.s8, B1, acc[0][1], 0, 0, 0);
      acc[1][0] = __builtin_amdgcn_mfma_f32_32x32x16_bf16(a1.s8, B0, acc[1][0], 0, 0, 0);
      acc[1][1] = __builtin_amdgcn_mfma_f32_32x32x16_bf16(a1.s8, B1, acc[1][1], 0, 0, 0);
      a0 = na0;
      a1 = na1;
    }
  }

  int py = py0 + pxq;
#pragma unroll
  for (int osub = 0; osub < 2; ++osub)
#pragma unroll
    for (int psub = 0; psub < 2; ++psub) {
      int OC = oc0 + ocq * 64 + osub * 32 + 4 * half;
      int pxc = psub * 32 + n;
      float* op = out + (((size_t)(b * NC + OC)) * 64 + py) * 64 + pxc;
#pragma unroll
      for (int reg = 0; reg < 16; ++reg) {
        int ocm = (reg & 3) + 8 * (reg >> 2);
        op[(size_t)ocm * 4096] = acc[osub][psub][reg];
      }
    }
}

extern "C" void kernel_launch(void* const* d_in, const int* in_sizes, int n_in,
                              void* d_out, int out_size, void* d_ws,
                              size_t ws_size, hipStream_t stream) {
  const float* x = (const float*)d_in[0];
  const float* dw = (const float*)d_in[1];
  const float* ka = (const float*)d_in[2];
  const int* fh = (const int*)d_in[3];
  const int* fw = (const int*)d_in[4];
  float* out = (float*)d_out;
  unsigned int* ws = (unsigned int*)d_ws;
  const unsigned short* specB = (const unsigned short*)d_ws;
  const unsigned short* Atw = (const unsigned short*)((char*)d_ws + 6291456);
  unsigned short* Ya = (unsigned short*)((char*)d_ws + 11010048);
  const unsigned short* T = (const unsigned short*)((char*)d_ws + 15925248);
  float* SW = (float*)d_ws;
  unsigned short* wBF = (unsigned short*)((char*)d_ws + WBF_BYTE);

  hipLaunchKernelGGL(prep_kernel, dim3(11364), dim3(256), 0, stream, dw, fh,
                     fw, ws);
  hipLaunchKernelGGL(fftA_kernel, dim3(12, 7, 8), dim3(256), 0, stream, Atw,
                     specB, Ya);
  hipLaunchKernelGGL(fftB_kernel, dim3(12, 12, KNUM), dim3(256), 0, stream, Ya,
                     T, SW);
  hipLaunchKernelGGL(wprep_kernel, dim3(144), dim3(256), 0, stream, ka, SW,
                     wBF);
  hipLaunchKernelGGL(conv_mfma_kernel, dim3(32, 2, NB), dim3(256), 0, stream,
                     x, wBF, out);
}

// Round 7
// 201.092 us; speedup vs baseline: 9.4760x; 1.1000x over previous
//
#include <hip/hip_runtime.h>
#include <math.h>

#define D1 768
#define D2R 385
#define NF 295680   // 768*385
#define KNUM 4
#define NB 8
#define NC 256
#define TWOPI_768 0.008181230868723419f

// ---------------- ws layout (bytes) --------------------------------------
// specB  bf16 [4][448 c-rows][1536 k]   @ 0          (6,291,456 B)  B^T stage A
// Atw    bf16 [2][768 m][1536 k]        @ 6,291,456  (4,718,592 B)  A stage A
// Ya     bf16 [4][768 m][800 k]         @ 11,010,048 (4,915,200 B)  A stage B
// T      bf16 [768 n][800 k]            @ 15,925,248 (1,228,800 B)  B^T stage B
// SW     f32  [4][768][768]             @ 0          (9,437,184 B)  overlays specB+Atw (dead)
// wBF    bf16 [8][16][9][256][16]       @ 9,437,184  (9,437,184 B)  overlays Ya+T (dead)
#define ATW_U32 1572864u
#define YA_U32 2752512u
#define T_U32 3981312u
#define SPECB_K_U32 344064u  // 448*768 uints per k
#define WBF_BYTE 9437184u

typedef __attribute__((ext_vector_type(8))) short short8;
typedef __attribute__((ext_vector_type(16))) float f32x16;
union U4S8 { unsigned int u[4]; uint4 u4; short8 s8; };

static __device__ __forceinline__ unsigned int f2bf(float f) {
  unsigned int u = __float_as_uint(f);
  return (u + 0x7fffu + ((u >> 16) & 1u)) >> 16;  // RNE, no NaN inputs
}

// ---------------- prep: scatter + twiddle matrices + zero pads -----------
__global__ __launch_bounds__(256) void prep_kernel(
    const float* __restrict__ dw, const int* __restrict__ fh,
    const int* __restrict__ fw, unsigned int* __restrict__ ws) {
  long i = (long)blockIdx.x * 256 + threadIdx.x;  // grid 11364
  if (i < 1182720) {  // scatter: dft_weight -> bf16 B^T spectrum
    int k = (int)(i / NF);
    int r = (int)(i - (long)k * NF);
    const float2 v = ((const float2*)dw)[i];
    int h = fh[r], c = fw[r];
    ws[(size_t)k * SPECB_K_U32 + (size_t)c * 768 + h] =
        f2bf(v.x) | (f2bf(v.y) << 16);
    return;
  }
  long j = i - 1182720;
  if (j < 1179648) {  // Atw: A_re/A_im [768 m][1536 k=2h]
    int ri = (int)(j / 589824);
    int rem = (int)(j - (long)ri * 589824);
    int m = rem / 768, h = rem - (rem / 768) * 768;
    int idx = (h * m) % 768;
    float s, c;
    sincosf((float)idx * TWOPI_768, &s, &c);
    unsigned lo, hi;
    if (ri == 0) { lo = f2bf(c); hi = f2bf(-s); }
    else         { lo = f2bf(s); hi = f2bf(c); }
    ws[ATW_U32 + j] = lo | (hi << 16);
  } else if (j < 1486848) {  // T^T [768 n][800 k=2c]
    long p = j - 1179648;
    int n = (int)(p / 400), cc = (int)(p - (p / 400) * 400);
    unsigned v = 0;
    if (cc <= 384) {
      float wgt = (cc == 0 || cc == 384) ? 1.6954210069444445e-6f
                                         : 3.390842013888889e-6f;
      int idx = (cc * n) % 768;
      float s, c;
      sincosf((float)idx * TWOPI_768, &s, &c);
      v = f2bf(wgt * c) | (f2bf(-wgt * s) << 16);
    }
    ws[T_U32 + (size_t)n * 400 + cc] = v;
  } else if (j < 1680384) {  // specB zero rows 385..447
    long p = j - 1486848;
    int k = (int)(p / 48384);
    long r = p - (long)k * 48384;
    int row = 385 + (int)(r / 768);
    int col = (int)(r - (r / 768) * 768);
    ws[(size_t)k * SPECB_K_U32 + (size_t)row * 768 + col] = 0u;
  } else if (j < 1726464) {  // Ya zero cols 770..799
    long p = j - 1680384;
    int k = (int)(p / 11520);
    long r = p - (long)k * 11520;
    int m = (int)(r / 15), jj = (int)(r - (r / 15) * 15);
    ws[YA_U32 + (size_t)k * 307200 + (size_t)m * 400 + 385 + jj] = 0u;
  }
}

// ---------------- fftA: dbuf bf16 MFMA GEMM, M=768 N=448(385) K=1536 -----
__global__ __launch_bounds__(256) void fftA_kernel(
    const unsigned short* __restrict__ Atw,
    const unsigned short* __restrict__ specB,
    unsigned short* __restrict__ Ya) {
  __shared__ __align__(16) unsigned short Al[2][64 * 40], Bl[2][64 * 40];
  int t = threadIdx.x;
  int mt = blockIdx.x, nt = blockIdx.y, z = blockIdx.z;
  int ri = z & 1, k = z >> 1;
  const unsigned short* Ag =
      Atw + (size_t)ri * 1179648 + (size_t)(mt * 64) * 1536;
  const unsigned short* Bg =
      specB + (size_t)k * 688128 + (size_t)(nt * 64) * 1536;
  int rowS = t >> 2, q = t & 3;
  int lane = t & 63, w = t >> 6;
  int moff = (w & 1) * 32, noff = (w >> 1) * 32;
  int lm = lane & 31, half = lane >> 5;
  int wr = rowS * 40 + q * 8;
  int ao = (moff + lm) * 40 + half * 8;
  int bo = (noff + lm) * 40 + half * 8;

  f32x16 acc;
#pragma unroll
  for (int r = 0; r < 16; ++r) acc[r] = 0.f;

  uint4 av = *(const uint4*)(Ag + (size_t)rowS * 1536 + q * 8);
  uint4 bv = *(const uint4*)(Bg + (size_t)rowS * 1536 + q * 8);
  *(uint4*)&Al[0][wr] = av;
  *(uint4*)&Bl[0][wr] = bv;
  __syncthreads();

  for (int kb = 0; kb < 48; ++kb) {
    bool more = (kb < 47);
    if (more) {
      av = *(const uint4*)(Ag + (size_t)rowS * 1536 + (kb + 1) * 32 + q * 8);
      bv = *(const uint4*)(Bg + (size_t)rowS * 1536 + (kb + 1) * 32 + q * 8);
    }
    const unsigned short* Ab = Al[kb & 1];
    const unsigned short* Bb = Bl[kb & 1];
#pragma unroll
    for (int kk2 = 0; kk2 < 2; ++kk2) {
      short8 a8 = *(const short8*)&Ab[ao + kk2 * 16];
      short8 b8 = *(const short8*)&Bb[bo + kk2 * 16];
      acc = __builtin_amdgcn_mfma_f32_32x32x16_bf16(a8, b8, acc, 0, 0, 0);
    }
    if (more) {
      *(uint4*)&Al[(kb + 1) & 1][wr] = av;
      *(uint4*)&Bl[(kb + 1) & 1][wr] = bv;
    }
    __syncthreads();
  }

  int c = nt * 64 + noff + lm;
  if (c < D2R) {
    unsigned short* Yk = Ya + (size_t)k * 614400;
    int mb = mt * 64 + moff + 4 * half;
#pragma unroll
    for (int reg = 0; reg < 16; ++reg) {
      int m = mb + (reg & 3) + 8 * (reg >> 2);
      Yk[(size_t)m * 800 + 2 * c + ri] = (unsigned short)f2bf(acc[reg]);
    }
  }
}

// ---------------- fftB: dbuf bf16 MFMA GEMM, M=768 N=768 K=800 -----------
__global__ __launch_bounds__(256) void fftB_kernel(
    const unsigned short* __restrict__ Ya, const unsigned short* __restrict__ T,
    float* __restrict__ SW) {
  __shared__ __align__(16) unsigned short Al[2][64 * 40], Bl[2][64 * 40];
  int t = threadIdx.x;
  int mt = blockIdx.x, nt = blockIdx.y, k = blockIdx.z;
  const unsigned short* Ag = Ya + (size_t)k * 614400 + (size_t)(mt * 64) * 800;
  const unsigned short* Bg = T + (size_t)(nt * 64) * 800;
  int rowS = t >> 2, q = t & 3;
  int lane = t & 63, w = t >> 6;
  int moff = (w & 1) * 32, noff = (w >> 1) * 32;
  int lm = lane & 31, half = lane >> 5;
  int wr = rowS * 40 + q * 8;
  int ao = (moff + lm) * 40 + half * 8;
  int bo = (noff + lm) * 40 + half * 8;

  f32x16 acc;
#pragma unroll
  for (int r = 0; r < 16; ++r) acc[r] = 0.f;

  uint4 av = *(const uint4*)(Ag + (size_t)rowS * 800 + q * 8);
  uint4 bv = *(const uint4*)(Bg + (size_t)rowS * 800 + q * 8);
  *(uint4*)&Al[0][wr] = av;
  *(uint4*)&Bl[0][wr] = bv;
  __syncthreads();

  for (int kb = 0; kb < 25; ++kb) {
    bool more = (kb < 24);
    if (more) {
      av = *(const uint4*)(Ag + (size_t)rowS * 800 + (kb + 1) * 32 + q * 8);
      bv = *(const uint4*)(Bg + (size_t)rowS * 800 + (kb + 1) * 32 + q * 8);
    }
    const unsigned short* Ab = Al[kb & 1];
    const unsigned short* Bb = Bl[kb & 1];
#pragma unroll
    for (int kk2 = 0; kk2 < 2; ++kk2) {
      short8 a8 = *(const short8*)&Ab[ao + kk2 * 16];
      short8 b8 = *(const short8*)&Bb[bo + kk2 * 16];
      acc = __builtin_amdgcn_mfma_f32_32x32x16_bf16(a8, b8, acc, 0, 0, 0);
    }
    if (more) {
      *(uint4*)&Al[(kb + 1) & 1][wr] = av;
      *(uint4*)&Bl[(kb + 1) & 1][wr] = bv;
    }
    __syncthreads();
  }

  float* SWk = SW + (size_t)k * 589824;
  int n = nt * 64 + noff + lm;
  int mb = mt * 64 + moff + 4 * half;
#pragma unroll
  for (int reg = 0; reg < 16; ++reg) {
    int m = mb + (reg & 3) + 8 * (reg >> 2);
    SWk[(size_t)m * 768 + n] = acc[reg];
  }
}

// ---------------- wprep: b-loop inside; layout [b][icb][s][oc][16] -------
__global__ __launch_bounds__(256) void wprep_kernel(
    const float* __restrict__ ka, const float* __restrict__ SW,
    unsigned short* __restrict__ wBF) {
  int task = blockIdx.x * 256 + threadIdx.x;  // grid 144 -> 36864
  int oc = task & 255;
  int rest = task >> 8;   // 0..143
  int icb = rest & 15;
  int s = rest >> 4;      // 0..8
  int dy = s / 3, dx = s - dy * 3;

  float att[8][4];
#pragma unroll
  for (int b = 0; b < 8; ++b)
#pragma unroll
    for (int k = 0; k < 4; ++k)
      att[b][k] = 0.5f / (1.f + expf(-ka[b * 4 + k]));

  const float* r0 = SW + ((size_t)(oc * 3 + dy)) * D1 + icb * 48 + dx;
  const float* r1 = r0 + 589824;
  const float* r2 = r1 + 589824;
  const float* r3 = r2 + 589824;
  float v0[16], v1[16], v2[16], v3[16];
#pragma unroll
  for (int i = 0; i < 16; ++i) {
    v0[i] = r0[i * 3]; v1[i] = r1[i * 3];
    v2[i] = r2[i * 3]; v3[i] = r3[i * 3];
  }
#pragma unroll
  for (int b = 0; b < 8; ++b) {
    unsigned short ov[16];
#pragma unroll
    for (int i = 0; i < 16; ++i) {
      float v = att[b][0] * v0[i] + att[b][1] * v1[i] + att[b][2] * v2[i] +
                att[b][3] * v3[i];
      ov[i] = (unsigned short)f2bf(v);
    }
    uint4* dst =
        (uint4*)(wBF + ((((size_t)(b * 16 + icb) * 9 + s) * 256 + oc) * 16));
    dst[0] = *(uint4*)&ov[0];
    dst[1] = *(uint4*)&ov[8];
  }
}

// ---------------- conv v4: A-global ring(3) + x dbuf, 1 barrier/icb ------
__global__ __launch_bounds__(256, 2) void conv_mfma_kernel(
    const float* __restrict__ x, const unsigned short* __restrict__ wBF,
    float* __restrict__ out) {
  __shared__ __align__(16) unsigned char ldsX[2][4 * 66 * 48];
  int t = threadIdx.x;
  int pxt = blockIdx.x, oct = blockIdx.y, b = blockIdx.z;
  int py0 = pxt * 2, oc0 = oct * 128;
  int lane = t & 63, w = t >> 6;
  int ocq = w >> 1, pxq = w & 1;
  int n = lane & 31, half = lane >> 5;

  // zero halo cols (c=0,65; rows 0..3) in both buffers, once
  if (t < 192) {
    int buf = t / 96, r2 = t - buf * 96;
    int site = r2 / 12, word = r2 - site * 12;
    int r = site >> 1, c = (site & 1) ? 65 : 0;
    *(unsigned int*)(&ldsX[buf][(r * 66 + c) * 48 + word * 4]) = 0u;
  }

  f32x16 acc[2][2];
#pragma unroll
  for (int i = 0; i < 2; ++i)
#pragma unroll
    for (int j = 0; j < 2; ++j)
#pragma unroll
      for (int r = 0; r < 16; ++r) acc[i][j][r] = 0.f;

  // x staging role
  int s_cq = t >> 5, s_r = (t >> 3) & 3, s_icp = t & 7;
  int iy = py0 - 1 + s_r;
  bool valid = (iy >= 0 && iy < 64);
  const float* xpb =
      x + (((size_t)b * NC) * 64 + (valid ? iy : 0)) * 64 + s_cq * 8;
  int xwoff = (s_r * 66 + 1 + s_cq * 8) * 48 + s_icp * 4;

  // A-frag ring (depth 3), layout [b][step=icb*9+s][oc][16]
  const uint4* wg4 = (const uint4*)wBF;
  size_t abase =
      (size_t)b * 144 * 512 + (size_t)(oc0 + ocq * 64 + n) * 2 + half;
  U4S8 pf[3][2];
#pragma unroll
  for (int i = 0; i < 3; ++i) {
    pf[i][0].u4 = wg4[abase + (size_t)i * 512];
    pf[i][1].u4 = wg4[abase + (size_t)i * 512 + 64];
  }

  // prologue: stage icb 0 into buf 0
  {
    float4 qa0 = make_float4(0.f, 0.f, 0.f, 0.f), qa1 = qa0, qb0 = qa0,
           qb1 = qa0;
    if (valid) {
      const float* p0 = xpb + (size_t)(s_icp * 2) * 4096;
      qa0 = *(const float4*)p0;
      qa1 = *(const float4*)(p0 + 4);
      qb0 = *(const float4*)(p0 + 4096);
      qb1 = *(const float4*)(p0 + 4100);
    }
    float av[8] = {qa0.x, qa0.y, qa0.z, qa0.w, qa1.x, qa1.y, qa1.z, qa1.w};
    float bv[8] = {qb0.x, qb0.y, qb0.z, qb0.w, qb1.x, qb1.y, qb1.z, qb1.w};
    unsigned char* xw = &ldsX[0][0] + xwoff;
#pragma unroll
    for (int j = 0; j < 8; ++j)
      *(unsigned int*)(xw + j * 48) = f2bf(av[j]) | (f2bf(bv[j]) << 16);
  }
  __syncthreads();

  for (int icb = 0; icb < 16; ++icb) {
    // issue next x-tile loads (cover = this icb's 36 mfma)
    float4 qa0 = make_float4(0.f, 0.f, 0.f, 0.f), qa1 = qa0, qb0 = qa0,
           qb1 = qa0;
    if (icb < 15 && valid) {
      const float* p0 = xpb + ((size_t)(icb + 1) * 16 + s_icp * 2) * 4096;
      qa0 = *(const float4*)p0;
      qa1 = *(const float4*)(p0 + 4);
      qb0 = *(const float4*)(p0 + 4096);
      qb1 = *(const float4*)(p0 + 4100);
    }
    const unsigned char* bufR = &ldsX[icb & 1][0];
#pragma unroll
    for (int s = 0; s < 9; ++s) {
      int step = icb * 9 + s;
      int slot = s % 3;
      int dy = s / 3, dx = s - dy * 3;
      const unsigned char* bb =
          bufR + ((pxq + dy) * 66 + n + dx) * 48 + half * 16;
      short8 B0 = *(const short8*)bb;
      short8 B1 = *(const short8*)(bb + 32 * 48);
      acc[0][0] = __builtin_amdgcn_mfma_f32_32x32x16_bf16(pf[slot][0].s8, B0,
                                                          acc[0][0], 0, 0, 0);
      acc[0][1] = __builtin_amdgcn_mfma_f32_32x32x16_bf16(pf[slot][0].s8, B1,
                                                          acc[0][1], 0, 0, 0);
      acc[1][0] = __builtin_amdgcn_mfma_f32_32x32x16_bf16(pf[slot][1].s8, B0,
                                                          acc[1][0], 0, 0, 0);
      acc[1][1] = __builtin_amdgcn_mfma_f32_32x32x16_bf16(pf[slot][1].s8, B1,
                                                          acc[1][1], 0, 0, 0);
      if (step + 3 < 144) {  // refill ring slot (WAR after mfma issue)
        pf[slot][0].u4 = wg4[abase + (size_t)(step + 3) * 512];
        pf[slot][1].u4 = wg4[abase + (size_t)(step + 3) * 512 + 64];
      }
    }
    if (icb < 15) {  // convert + write next tile into other buffer
      float av[8] = {qa0.x, qa0.y, qa0.z, qa0.w, qa1.x, qa1.y, qa1.z, qa1.w};
      float bv[8] = {qb0.x, qb0.y, qb0.z, qb0.w, qb1.x, qb1.y, qb1.z, qb1.w};
      unsigned char* xw = &ldsX[(icb + 1) & 1][0] + xwoff;
#pragma unroll
      for (int j = 0; j < 8; ++j)
        *(unsigned int*)(xw + j * 48) = f2bf(av[j]) | (f2bf(bv[j]) << 16);
    }
    __syncthreads();
  }

  int py = py0 + pxq;
#pragma unroll
  for (int osub = 0; osub < 2; ++osub)
#pragma unroll
    for (int psub = 0; psub < 2; ++psub) {
      int OC = oc0 + ocq * 64 + osub * 32 + 4 * half;
      int pxc = psub * 32 + n;
      float* op = out + (((size_t)(b * NC + OC)) * 64 + py) * 64 + pxc;
#pragma unroll
      for (int reg = 0; reg < 16; ++reg) {
        int ocm = (reg & 3) + 8 * (reg >> 2);
        op[(size_t)ocm * 4096] = acc[osub][psub][reg];
      }
    }
}

extern "C" void kernel_launch(void* const* d_in, const int* in_sizes, int n_in,
                              void* d_out, int out_size, void* d_ws,
                              size_t ws_size, hipStream_t stream) {
  const float* x = (const float*)d_in[0];
  const float* dw = (const float*)d_in[1];
  const float* ka = (const float*)d_in[2];
  const int* fh = (const int*)d_in[3];
  const int* fw = (const int*)d_in[4];
  float* out = (float*)d_out;
  unsigned int* ws = (unsigned int*)d_ws;
  const unsigned short* specB = (const unsigned short*)d_ws;
  const unsigned short* Atw = (const unsigned short*)((char*)d_ws + 6291456);
  unsigned short* Ya = (unsigned short*)((char*)d_ws + 11010048);
  const unsigned short* T = (const unsigned short*)((char*)d_ws + 15925248);
  float* SW = (float*)d_ws;
  unsigned short* wBF = (unsigned short*)((char*)d_ws + WBF_BYTE);

  hipLaunchKernelGGL(prep_kernel, dim3(11364), dim3(256), 0, stream, dw, fh,
                     fw, ws);
  hipLaunchKernelGGL(fftA_kernel, dim3(12, 7, 8), dim3(256), 0, stream, Atw,
                     specB, Ya);
  hipLaunchKernelGGL(fftB_kernel, dim3(12, 12, KNUM), dim3(256), 0, stream, Ya,
                     T, SW);
  hipLaunchKernelGGL(wprep_kernel, dim3(144), dim3(256), 0, stream, ka, SW,
                     wBF);
  hipLaunchKernelGGL(conv_mfma_kernel, dim3(32, 2, NB), dim3(256), 0, stream,
                     x, wBF, out);
}